// Round 9
// baseline (798.016 us; speedup 1.0000x reference)
//
#include <hip/hip_runtime.h>
#include <hip/hip_bf16.h>

#define Nn 50000
#define Ee 800000
#define INF_ 128
#define HIDF 96
#define HH 8
#define DD 12
#define GG 64
#define OUTF 10

#define SCAN_CHUNK 512
#define SCAN_BLOCKS ((Nn + SCAN_CHUNK - 1) / SCAN_CHUNK)   // 98
#define RB 128   // readout partial blocks

// byte-packed LDS histogram CSR build
#define HCHK 256                // edge chunks (= blocks)
#define HCHKE (Ee / HCHK)       // 3125 edges per chunk
#define NW 12512                // packed words: 4 keys/word, 50048 >= Nn
#define DBIN 64                 // degree bins for counting sort

// ---------------- hist pass A: byte-packed LDS histograms; returns per-edge slot ----------------
__global__ __launch_bounds__(256) void hist_lds(const int* __restrict__ src,
                                                const int* __restrict__ dst,
                                                unsigned int* __restrict__ partS,
                                                unsigned int* __restrict__ partD,
                                                int* __restrict__ edge_slot) {
    __shared__ unsigned int h[NW];
    int b = blockIdx.x, t = threadIdx.x;
    for (int i = t; i < NW; i += 256) h[i] = 0u;
    __syncthreads();
    int base = b * HCHKE;
    for (int i = t; i < HCHKE; i += 256) {
        int d = dst[base + i];
        unsigned int old = atomicAdd(&h[d >> 2], 1u << ((d & 3) * 8));
        edge_slot[base + i] = (int)((old >> ((d & 3) * 8)) & 0xFFu);
    }
    __syncthreads();
    for (int i = t; i < NW; i += 256) { partD[(size_t)b * NW + i] = h[i]; h[i] = 0u; }
    __syncthreads();
    for (int i = t; i < HCHKE; i += 256) {
        int s = src[base + i];
        atomicAdd(&h[s >> 2], 1u << ((s & 3) * 8));
    }
    __syncthreads();
    for (int i = t; i < NW; i += 256) partS[(size_t)b * NW + i] = h[i];
}

// ---------------- hist pass B: packed chunk-exclusive prefix on partD; totals -> cnt ----------------
__global__ void hist_scan(unsigned int* __restrict__ partD,
                          const unsigned int* __restrict__ partS,
                          int* __restrict__ cnt_in, int* __restrict__ cnt_out) {
    int w = blockIdx.x * 256 + threadIdx.x;
    if (w >= NW) return;
    unsigned int run = 0u, totS = 0u;
    for (int b = 0; b < HCHK; ++b) {
        size_t idx = (size_t)b * NW + w;
        unsigned int v = partD[idx];
        partD[idx] = run;               // exclusive prefix across chunks (packed bytes)
        run += v;
        totS += partS[idx];
    }
#pragma unroll
    for (int j = 0; j < 4; ++j) {
        int k = w * 4 + j;
        if (k < Nn) {
            cnt_in[k]  = (int)((run >> (j * 8)) & 0xFFu);
            cnt_out[k] = (int)((totS >> (j * 8)) & 0xFFu);
        }
    }
}

// ---------------- hierarchical scan, stage 1 ----------------
__global__ __launch_bounds__(256) void scan1_kernel(const int* __restrict__ cnt,
                                                    int* __restrict__ row_start,
                                                    int* __restrict__ blk_sum, int N) {
    __shared__ int part[256];
    int t = threadIdx.x;
    int base = blockIdx.x * SCAN_CHUNK;
    int i0 = base + 2 * t, i1 = i0 + 1;
    int a = (i0 < N) ? cnt[i0] : 0;
    int b = (i1 < N) ? cnt[i1] : 0;
    int s = a + b;
    part[t] = s;
    __syncthreads();
    for (int off = 1; off < 256; off <<= 1) {
        int v = (t >= off) ? part[t - off] : 0;
        __syncthreads();
        part[t] += v;
        __syncthreads();
    }
    int excl = part[t] - s;
    if (i0 < N) row_start[i0] = excl;
    if (i1 < N) row_start[i1] = excl + a;
    if (t == 255) blk_sum[blockIdx.x] = part[255];
}

// ---------------- stage 2: scan block sums ----------------
__global__ __launch_bounds__(128) void scan2_kernel(const int* __restrict__ blk_sum,
                                                    int* __restrict__ blk_off,
                                                    int* __restrict__ row_start, int N) {
    __shared__ int part[128];
    int t = threadIdx.x;
    int v0 = (t < SCAN_BLOCKS) ? blk_sum[t] : 0;
    part[t] = v0;
    __syncthreads();
    for (int off = 1; off < 128; off <<= 1) {
        int v = (t >= off) ? part[t - off] : 0;
        __syncthreads();
        part[t] += v;
        __syncthreads();
    }
    blk_off[t] = part[t] - v0;
    if (t == 127) row_start[N] = part[127];
}

// ---------------- stage 3: add block offsets ----------------
__global__ __launch_bounds__(256) void scan3_kernel(int* __restrict__ row_start,
                                                    const int* __restrict__ blk_off, int N) {
    int t = threadIdx.x;
    int base = blockIdx.x * SCAN_CHUNK;
    int off = blk_off[blockIdx.x];
    int i0 = base + 2 * t, i1 = i0 + 1;
    if (i0 < N) row_start[i0] += off;
    if (i1 < N) row_start[i1] += off;
}

// ---------------- per-node setup: inv-sqrt degrees ----------------
__global__ void node_setup(const int* __restrict__ cnt_in, const int* __restrict__ cnt_out,
                           float* __restrict__ degI_is, float* __restrict__ degO_is, int N) {
    int n = blockIdx.x * 256 + threadIdx.x;
    if (n < N) {
        degI_is[n] = rsqrtf((float)max(cnt_in[n], 1));
        degO_is[n] = rsqrtf((float)max(cnt_out[n], 1));
    }
}

// ---------------- CSR fill: atomic-free ----------------
__global__ __launch_bounds__(256) void fill_kernel(const int* __restrict__ src,
                                                   const int* __restrict__ dst,
                                                   const int* __restrict__ row_start,
                                                   const unsigned int* __restrict__ partD,
                                                   const int* __restrict__ edge_slot,
                                                   int* __restrict__ csr_src) {
    int b = blockIdx.x, t = threadIdx.x;
    int base = b * HCHKE;
    size_t po = (size_t)b * NW;
    for (int i = t; i < HCHKE; i += 256) {
        int e = base + i;
        int d = dst[e];
        int cb = (int)((partD[po + (d >> 2)] >> ((d & 3) * 8)) & 0xFFu);
        csr_src[row_start[d] + cb + edge_slot[e]] = src[e];
    }
}

// ---------------- degree counting sort (DESCENDING: LPT scheduling) ----------------
__global__ __launch_bounds__(256) void deg_hist(const int* __restrict__ cnt_in,
                                                int* __restrict__ dcnt, int N) {
    __shared__ int h[DBIN];
    int t = threadIdx.x;
    if (t < DBIN) h[t] = 0;
    __syncthreads();
    int n = blockIdx.x * 256 + t;
    if (n < N) atomicAdd(&h[DBIN - 1 - min(cnt_in[n], DBIN - 1)], 1);
    __syncthreads();
    if (t < DBIN && h[t]) atomicAdd(&dcnt[t], h[t]);
}

__global__ __launch_bounds__(64) void deg_scan(const int* __restrict__ dcnt,
                                               int* __restrict__ dcur) {
    __shared__ int p[DBIN];
    int t = threadIdx.x;
    int v0 = dcnt[t];
    p[t] = v0;
    __syncthreads();
    for (int o = 1; o < DBIN; o <<= 1) {
        int v = (t >= o) ? p[t - o] : 0;
        __syncthreads();
        p[t] += v;
        __syncthreads();
    }
    dcur[t] = p[t] - v0;   // exclusive
}

__global__ __launch_bounds__(256) void perm_fill(const int* __restrict__ cnt_in,
                                                 int* __restrict__ dcur,
                                                 int* __restrict__ perm, int N) {
    __shared__ int lh[DBIN];
    __shared__ int lbase[DBIN];
    int t = threadIdx.x;
    if (t < DBIN) lh[t] = 0;
    __syncthreads();
    int n = blockIdx.x * 256 + t;
    int bin = 0, lslot = 0;
    if (n < N) {
        bin = DBIN - 1 - min(cnt_in[n], DBIN - 1);
        lslot = atomicAdd(&lh[bin], 1);
    }
    __syncthreads();
    if (t < DBIN) lbase[t] = lh[t] ? atomicAdd(&dcur[t], lh[t]) : 0;
    __syncthreads();
    if (n < N) perm[lbase[bin] + lslot] = n;
}

// ---------------- staged-LDS GEMM; output in SLICED layout out[s][N][12], s=col/12 ----------------
__global__ __launch_bounds__(192) void gemm96(const float* __restrict__ A, int K,
                                              const float* __restrict__ W,
                                              const float* __restrict__ bias,
                                              const float* __restrict__ rowScale,
                                              float* __restrict__ out, int N) {
    __shared__ float A_lds[64 * 36];
    __shared__ float W_lds[32 * 96];
    const int t = threadIdx.x;
    const int row0 = blockIdx.x * 64;
    const int tcol = t % 24;
    const int trow = t / 24;
    const int sl = tcol / 3;           // slice 0..7
    const int dof = (tcol % 3) * 4;    // offset within slice
    float acc[8][4];
#pragma unroll
    for (int i = 0; i < 8; ++i)
#pragma unroll
        for (int j = 0; j < 4; ++j) acc[i][j] = 0.f;

    for (int k0 = 0; k0 < K; k0 += 32) {
        for (int i = t; i < 32 * 24; i += 192) {
            ((float4*)W_lds)[i] = ((const float4*)W)[(size_t)k0 * 24 + i];
        }
        for (int i = t; i < 64 * 8; i += 192) {
            int r = i / 8, kk = i % 8;
            int gr = row0 + r;
            float4 v = make_float4(0.f, 0.f, 0.f, 0.f);
            if (gr < N) {
                v = *((const float4*)(A + (size_t)gr * K + k0 + kk * 4));
                if (rowScale) {
                    float s = rowScale[gr];
                    v.x *= s; v.y *= s; v.z *= s; v.w *= s;
                }
            }
            *((float4*)(A_lds + r * 36 + kk * 4)) = v;
        }
        __syncthreads();
#pragma unroll
        for (int kk4 = 0; kk4 < 8; ++kk4) {
            float4 a[8];
#pragma unroll
            for (int i = 0; i < 8; ++i)
                a[i] = *((const float4*)(A_lds + (trow + 8 * i) * 36 + kk4 * 4));
#pragma unroll
            for (int kk = 0; kk < 4; ++kk) {
                float4 wv = *((const float4*)(W_lds + (kk4 * 4 + kk) * 96 + tcol * 4));
#pragma unroll
                for (int i = 0; i < 8; ++i) {
                    float av = (kk == 0) ? a[i].x : (kk == 1) ? a[i].y : (kk == 2) ? a[i].z : a[i].w;
                    acc[i][0] = fmaf(av, wv.x, acc[i][0]);
                    acc[i][1] = fmaf(av, wv.y, acc[i][1]);
                    acc[i][2] = fmaf(av, wv.z, acc[i][2]);
                    acc[i][3] = fmaf(av, wv.w, acc[i][3]);
                }
            }
        }
        __syncthreads();
    }
    float4 b4 = bias ? *((const float4*)(bias + tcol * 4)) : make_float4(0.f, 0.f, 0.f, 0.f);
#pragma unroll
    for (int i = 0; i < 8; ++i) {
        int gr = row0 + trow + 8 * i;
        if (gr < N) {
            float4 o = make_float4(acc[i][0] + b4.x, acc[i][1] + b4.y,
                                   acc[i][2] + b4.z, acc[i][3] + b4.w);
            *((float4*)(out + (size_t)sl * N * 12 + (size_t)gr * 12 + dof)) = o;
        }
    }
}

// ---------------- dual GEMM; both outputs HEAD-MAJOR [8][N][12] ----------------
__global__ __launch_bounds__(192) void gemm96x2(const float* __restrict__ A,
                                                const float* __restrict__ W1_, const float* __restrict__ b1_,
                                                const float* __restrict__ W2_, const float* __restrict__ b2_,
                                                float* __restrict__ out1, float* __restrict__ out2, int N) {
    __shared__ float A_lds[64 * 36];
    __shared__ float W_lds[2 * 32 * 96];
    const int t = threadIdx.x;
    const int row0 = blockIdx.x * 64;
    const int tcol = t % 24;
    const int trow = t / 24;
    const int sl = tcol / 3;
    const int dof = (tcol % 3) * 4;
    float acc1[8][4], acc2[8][4];
#pragma unroll
    for (int i = 0; i < 8; ++i)
#pragma unroll
        for (int j = 0; j < 4; ++j) { acc1[i][j] = 0.f; acc2[i][j] = 0.f; }

    for (int k0 = 0; k0 < 96; k0 += 32) {
        for (int i = t; i < 32 * 24; i += 192) {
            ((float4*)W_lds)[i] = ((const float4*)W1_)[(size_t)k0 * 24 + i];
            ((float4*)(W_lds + 32 * 96))[i] = ((const float4*)W2_)[(size_t)k0 * 24 + i];
        }
        for (int i = t; i < 64 * 8; i += 192) {
            int r = i / 8, kk = i % 8;
            int gr = row0 + r;
            float4 v = make_float4(0.f, 0.f, 0.f, 0.f);
            if (gr < N) v = *((const float4*)(A + (size_t)gr * 96 + k0 + kk * 4));
            *((float4*)(A_lds + r * 36 + kk * 4)) = v;
        }
        __syncthreads();
#pragma unroll
        for (int kk4 = 0; kk4 < 8; ++kk4) {
            float4 a[8];
#pragma unroll
            for (int i = 0; i < 8; ++i)
                a[i] = *((const float4*)(A_lds + (trow + 8 * i) * 36 + kk4 * 4));
#pragma unroll
            for (int kk = 0; kk < 4; ++kk) {
                float4 wv1 = *((const float4*)(W_lds + (kk4 * 4 + kk) * 96 + tcol * 4));
                float4 wv2 = *((const float4*)(W_lds + 32 * 96 + (kk4 * 4 + kk) * 96 + tcol * 4));
#pragma unroll
                for (int i = 0; i < 8; ++i) {
                    float av = (kk == 0) ? a[i].x : (kk == 1) ? a[i].y : (kk == 2) ? a[i].z : a[i].w;
                    acc1[i][0] = fmaf(av, wv1.x, acc1[i][0]);
                    acc1[i][1] = fmaf(av, wv1.y, acc1[i][1]);
                    acc1[i][2] = fmaf(av, wv1.z, acc1[i][2]);
                    acc1[i][3] = fmaf(av, wv1.w, acc1[i][3]);
                    acc2[i][0] = fmaf(av, wv2.x, acc2[i][0]);
                    acc2[i][1] = fmaf(av, wv2.y, acc2[i][1]);
                    acc2[i][2] = fmaf(av, wv2.z, acc2[i][2]);
                    acc2[i][3] = fmaf(av, wv2.w, acc2[i][3]);
                }
            }
        }
        __syncthreads();
    }
    float4 bb1 = *((const float4*)(b1_ + tcol * 4));
    float4 bb2 = *((const float4*)(b2_ + tcol * 4));
#pragma unroll
    for (int i = 0; i < 8; ++i) {
        int gr = row0 + trow + 8 * i;
        if (gr < N) {
            float4 o1 = make_float4(acc1[i][0] + bb1.x, acc1[i][1] + bb1.y,
                                    acc1[i][2] + bb1.z, acc1[i][3] + bb1.w);
            float4 o2 = make_float4(acc2[i][0] + bb2.x, acc2[i][1] + bb2.y,
                                    acc2[i][2] + bb2.z, acc2[i][3] + bb2.w);
            size_t oo = (size_t)sl * N * 12 + (size_t)gr * 12 + dof;
            *((float4*)(out1 + oo)) = o1;
            *((float4*)(out2 + oo)) = o2;
        }
    }
}

// ---------------- GraphConv aggregate: XCD column-slice (slice = blockIdx & 7) ----------------
// hW is sliced [8][N][12]; block handles 64 nodes x one 12-col slice; 3 threads/node.
__global__ __launch_bounds__(192) void gc_agg(const float* __restrict__ hW,
                                              const int* __restrict__ row_start,
                                              const int* __restrict__ csr_src,
                                              const float* __restrict__ degI_is,
                                              const float* __restrict__ bias,
                                              const int* __restrict__ perm,
                                              float* __restrict__ hout, int N) {
    int sl = blockIdx.x & 7;
    int t = threadIdx.x;
    int p = (blockIdx.x >> 3) * 64 + t / 3;
    int ch = (t % 3) * 4;
    if (p >= N) return;
    int n = perm[p];
    const float* tab = hW + (size_t)sl * N * 12;
    int beg = row_start[n], end = row_start[n + 1];
    float4 s = make_float4(0.f, 0.f, 0.f, 0.f);
    int e = beg;
    for (; e + 4 <= end; e += 4) {
        int i0 = csr_src[e], i1 = csr_src[e + 1], i2 = csr_src[e + 2], i3 = csr_src[e + 3];
        float4 v0 = *(const float4*)(tab + (size_t)i0 * 12 + ch);
        float4 v1 = *(const float4*)(tab + (size_t)i1 * 12 + ch);
        float4 v2 = *(const float4*)(tab + (size_t)i2 * 12 + ch);
        float4 v3 = *(const float4*)(tab + (size_t)i3 * 12 + ch);
        s.x += (v0.x + v1.x) + (v2.x + v3.x);
        s.y += (v0.y + v1.y) + (v2.y + v3.y);
        s.z += (v0.z + v1.z) + (v2.z + v3.z);
        s.w += (v0.w + v1.w) + (v2.w + v3.w);
    }
    for (; e < end; ++e) {
        int i0 = csr_src[e];
        float4 v0 = *(const float4*)(tab + (size_t)i0 * 12 + ch);
        s.x += v0.x; s.y += v0.y; s.z += v0.z; s.w += v0.w;
    }
    float dn = degI_is[n];
    float4 b = *(const float4*)(bias + sl * 12 + ch);
    float4 o;
    o.x = fmaxf(fmaf(s.x, dn, b.x), 0.f);
    o.y = fmaxf(fmaf(s.y, dn, b.y), 0.f);
    o.z = fmaxf(fmaf(s.z, dn, b.z), 0.f);
    o.w = fmaxf(fmaf(s.w, dn, b.w), 0.f);
    *(float4*)(hout + (size_t)n * 96 + sl * 12 + ch) = o;   // node-major for next GEMM
}

// ---------------- GATv2: head-per-block (head = blockIdx & 7), fs/fd head-major ----------------
__global__ __launch_bounds__(256) void gat_agg(const float* __restrict__ fs,
                                               const float* __restrict__ fd,
                                               const float* __restrict__ attn,
                                               const int* __restrict__ row_start,
                                               const int* __restrict__ csr_src,
                                               const int* __restrict__ perm,
                                               float* __restrict__ hout, int N) {
    int hd = blockIdx.x & 7;
    int p = (blockIdx.x >> 3) * 256 + threadIdx.x;
    if (p >= N) return;
    int n = perm[p];
    const float* tab = fs + (size_t)hd * N * 12;
    float att[12], fdv[12];
    {
        const float4* ap = (const float4*)(attn + hd * 12);
        float4 a0 = ap[0], a1 = ap[1], a2 = ap[2];
        att[0]=a0.x; att[1]=a0.y; att[2]=a0.z; att[3]=a0.w;
        att[4]=a1.x; att[5]=a1.y; att[6]=a1.z; att[7]=a1.w;
        att[8]=a2.x; att[9]=a2.y; att[10]=a2.z; att[11]=a2.w;
        const float4* dp = (const float4*)(fd + (size_t)hd * N * 12 + (size_t)n * 12);
        float4 d0 = dp[0], d1 = dp[1], d2 = dp[2];
        fdv[0]=d0.x; fdv[1]=d0.y; fdv[2]=d0.z; fdv[3]=d0.w;
        fdv[4]=d1.x; fdv[5]=d1.y; fdv[6]=d1.z; fdv[7]=d1.w;
        fdv[8]=d2.x; fdv[9]=d2.y; fdv[10]=d2.z; fdv[11]=d2.w;
    }
    int beg = row_start[n], end = row_start[n + 1];
    float m0 = -3.0e38f, den0 = 0.f, m1 = -3.0e38f, den1 = 0.f;
    float A0[12], A1[12];
#pragma unroll
    for (int d = 0; d < 12; ++d) { A0[d] = 0.f; A1[d] = 0.f; }

    auto proc = [&](const float4& s0, const float4& s1, const float4& s2,
                    float& m, float& den, float* acc) {
        float fsv[12];
        fsv[0]=s0.x; fsv[1]=s0.y; fsv[2]=s0.z; fsv[3]=s0.w;
        fsv[4]=s1.x; fsv[5]=s1.y; fsv[6]=s1.z; fsv[7]=s1.w;
        fsv[8]=s2.x; fsv[9]=s2.y; fsv[10]=s2.z; fsv[11]=s2.w;
        float logit = 0.f;
#pragma unroll
        for (int d = 0; d < 12; ++d) {
            float u = fsv[d] + fdv[d];
            u = u > 0.f ? u : 0.2f * u;
            logit = fmaf(u, att[d], logit);
        }
        float nm = fmaxf(m, logit);
        float cc = __expf(m - nm);
        float w  = __expf(logit - nm);
        den = fmaf(den, cc, w);
#pragma unroll
        for (int d = 0; d < 12; ++d) acc[d] = fmaf(acc[d], cc, w * fsv[d]);
        m = nm;
    };

    int e = beg;
    for (; e + 4 <= end; e += 4) {
        int i0 = csr_src[e], i1 = csr_src[e + 1], i2 = csr_src[e + 2], i3 = csr_src[e + 3];
        const float4* p0 = (const float4*)(tab + (size_t)i0 * 12);
        const float4* p1 = (const float4*)(tab + (size_t)i1 * 12);
        const float4* p2 = (const float4*)(tab + (size_t)i2 * 12);
        const float4* p3 = (const float4*)(tab + (size_t)i3 * 12);
        float4 a0 = p0[0], a1 = p0[1], a2 = p0[2];
        float4 b0 = p1[0], b1 = p1[1], b2 = p1[2];
        float4 c0 = p2[0], c1 = p2[1], c2 = p2[2];
        float4 d0 = p3[0], d1 = p3[1], d2 = p3[2];
        proc(a0, a1, a2, m0, den0, A0);
        proc(b0, b1, b2, m1, den1, A1);
        proc(c0, c1, c2, m0, den0, A0);
        proc(d0, d1, d2, m1, den1, A1);
    }
    for (; e < end; ++e) {
        int i0 = csr_src[e];
        const float4* p0 = (const float4*)(tab + (size_t)i0 * 12);
        float4 a0 = p0[0], a1 = p0[1], a2 = p0[2];
        proc(a0, a1, a2, m0, den0, A0);
    }
    float nm = fmaxf(m0, m1);
    float c0 = __expf(m0 - nm), c1 = __expf(m1 - nm);
    float den = den0 * c0 + den1 * c1;
    float inv = den > 0.f ? 1.f / den : 0.f;
    float* op = hout + (size_t)n * 96 + hd * 12;   // node-major for next GEMM / readout
#pragma unroll
    for (int d = 0; d < 12; ++d)
        op[d] = fmaxf((A0[d] * c0 + A1[d] * c1) * inv, 0.f);
}

// ---------------- per-graph max readout: stage 1, per-block LDS max -> partials ----------------
__global__ __launch_bounds__(384) void readout_partial(const float* __restrict__ h,
                                                       const int* __restrict__ graph_id,
                                                       float* __restrict__ partial, int N) {
    __shared__ int lhg[GG * 96];
    int t = threadIdx.x;
    for (int i = t; i < GG * 96; i += 384) lhg[i] = 0;
    __syncthreads();
    int f = t % 96, nl = t / 96;
    for (int n0 = blockIdx.x * 4; n0 < N; n0 += RB * 4) {
        int n = n0 + nl;
        if (n < N) {
            int g = graph_id[n];
            float v = h[(size_t)n * 96 + f];
            atomicMax(&lhg[g * 96 + f], __float_as_int(v));
        }
    }
    __syncthreads();
    for (int i = t; i < GG * 96; i += 384)
        partial[(size_t)blockIdx.x * (GG * 96) + i] = __int_as_float(lhg[i]);
}

// ---------------- readout stage 2: reduce partials ----------------
__global__ void readout_reduce(const float* __restrict__ partial, float* __restrict__ hg) {
    int i = blockIdx.x * 256 + threadIdx.x;
    if (i < GG * 96) {
        float m = 0.f;
        for (int b = 0; b < RB; ++b) m = fmaxf(m, partial[(size_t)b * (GG * 96) + i]);
        hg[i] = m;
    }
}

// ---------------- classifier MLP: one block per graph ----------------
__global__ __launch_bounds__(96) void mlp_kernel(const float* __restrict__ hg,
                                                 const float* __restrict__ Wc1, const float* __restrict__ bc1,
                                                 const float* __restrict__ Wc2, const float* __restrict__ bc2,
                                                 const float* __restrict__ Wc3, const float* __restrict__ bc3,
                                                 float* __restrict__ out) {
    int g = blockIdx.x;
    int t = threadIdx.x;
    __shared__ float z0[96], z1[96], z2[48];
    z0[t] = hg[(size_t)g * 96 + t];
    __syncthreads();
    float s = bc1[t];
    for (int k = 0; k < 96; ++k) s = fmaf(z0[k], Wc1[k * 96 + t], s);
    z1[t] = fmaxf(s, 0.f);
    __syncthreads();
    if (t < 48) {
        float s2 = bc2[t];
        for (int k = 0; k < 96; ++k) s2 = fmaf(z1[k], Wc2[k * 48 + t], s2);
        z2[t] = fmaxf(s2, 0.f);
    }
    __syncthreads();
    if (t < 10) {
        float s3 = bc3[t];
        for (int k = 0; k < 48; ++k) s3 = fmaf(z2[k], Wc3[k * 10 + t], s3);
        out[(size_t)g * 10 + t] = s3;
    }
}

extern "C" void kernel_launch(void* const* d_in, const int* in_sizes, int n_in,
                              void* d_out, int out_size, void* d_ws, size_t ws_size,
                              hipStream_t stream) {
    const float* x        = (const float*)d_in[0];
    const int*   src      = (const int*)d_in[1];
    const int*   dst      = (const int*)d_in[2];
    const int*   graph_id = (const int*)d_in[3];
    const float* W1  = (const float*)d_in[4];
    const float* b1  = (const float*)d_in[5];
    const float* W2  = (const float*)d_in[6];
    const float* b2  = (const float*)d_in[7];
    const float* Ws  = (const float*)d_in[8];
    const float* bs  = (const float*)d_in[9];
    const float* Wd  = (const float*)d_in[10];
    const float* bd  = (const float*)d_in[11];
    const float* attn = (const float*)d_in[12];
    const float* Wc1 = (const float*)d_in[13];
    const float* bc1 = (const float*)d_in[14];
    const float* Wc2 = (const float*)d_in[15];
    const float* bc2 = (const float*)d_in[16];
    const float* Wc3 = (const float*)d_in[17];
    const float* bc3 = (const float*)d_in[18];
    float* out = (float*)d_out;

    char* ws = (char*)d_ws;
    size_t off = 0;
    auto alloc = [&](size_t bytes) {
        char* p = ws + off;
        off = (off + bytes + 255) & ~(size_t)255;
        return p;
    };
    int*   cnt_in    = (int*)alloc(Nn * 4);
    int*   cnt_out   = (int*)alloc(Nn * 4);
    int*   row_start = (int*)alloc((Nn + 1) * 4);
    int*   edge_slot = (int*)alloc(Ee * 4);
    int*   csr_src   = (int*)alloc(Ee * 4);
    int*   perm      = (int*)alloc(Nn * 4);
    float* degI_is   = (float*)alloc(Nn * 4);
    float* degO_is   = (float*)alloc(Nn * 4);
    float* bufH      = (float*)alloc((size_t)Nn * 96 * 4);
    float* bufT      = (float*)alloc((size_t)Nn * 96 * 4);
    float* bufFd     = (float*)alloc((size_t)Nn * 96 * 4);
    float* hg        = (float*)alloc(GG * 96 * 4);
    float* partial   = (float*)alloc((size_t)RB * GG * 96 * 4);
    int*   blk_sum   = (int*)alloc(128 * 4);
    int*   blk_off   = (int*)alloc(128 * 4);
    int*   dcnt      = (int*)alloc(DBIN * 4);
    int*   dcur      = (int*)alloc(DBIN * 4);

    // packed histogram partials alias the (not-yet-used) feature buffers
    unsigned int* partS = (unsigned int*)bufT;
    unsigned int* partD = (unsigned int*)bufFd;

    hipMemsetAsync(dcnt, 0, DBIN * 4, stream);

    // ---- CSR build (no global atomics) ----
    hist_lds<<<HCHK, 256, 0, stream>>>(src, dst, partS, partD, edge_slot);
    hist_scan<<<(NW + 255) / 256, 256, 0, stream>>>(partD, partS, cnt_in, cnt_out);
    scan1_kernel<<<SCAN_BLOCKS, 256, 0, stream>>>(cnt_in, row_start, blk_sum, Nn);
    scan2_kernel<<<1, 128, 0, stream>>>(blk_sum, blk_off, row_start, Nn);
    scan3_kernel<<<SCAN_BLOCKS, 256, 0, stream>>>(row_start, blk_off, Nn);
    node_setup<<<(Nn + 255) / 256, 256, 0, stream>>>(cnt_in, cnt_out, degI_is, degO_is, Nn);
    fill_kernel<<<HCHK, 256, 0, stream>>>(src, dst, row_start, partD, edge_slot, csr_src);

    // ---- degree counting sort (descending) -> perm ----
    deg_hist<<<(Nn + 255) / 256, 256, 0, stream>>>(cnt_in, dcnt, Nn);
    deg_scan<<<1, 64, 0, stream>>>(dcnt, dcur);
    perm_fill<<<(Nn + 255) / 256, 256, 0, stream>>>(cnt_in, dcur, perm, Nn);

    int gemm_blocks = (Nn + 63) / 64;
    int gc_blocks   = 8 * ((Nn + 63) / 64);
    int gat_blocks  = 8 * ((Nn + 255) / 256);

    // GraphConv 1: x[N,128] -> bufT (sliced) -> bufH (node-major)
    gemm96<<<gemm_blocks, 192, 0, stream>>>(x, 128, W1, nullptr, degO_is, bufT, Nn);
    gc_agg<<<gc_blocks, 192, 0, stream>>>(bufT, row_start, csr_src, degI_is, b1, perm, bufH, Nn);
    // GraphConv 2
    gemm96<<<gemm_blocks, 192, 0, stream>>>(bufH, 96, W2, nullptr, degO_is, bufT, Nn);
    gc_agg<<<gc_blocks, 192, 0, stream>>>(bufT, row_start, csr_src, degI_is, b2, perm, bufH, Nn);

    // 3x GATv2: dual GEMM (head-major fs/fd) then head-per-block attention+aggregate
    for (int l = 0; l < 3; ++l) {
        const float* Wsl = Ws + (size_t)l * 96 * 96;
        const float* bsl = bs + (size_t)l * 96;
        const float* Wdl = Wd + (size_t)l * 96 * 96;
        const float* bdl = bd + (size_t)l * 96;
        const float* atl = attn + (size_t)l * 96;
        gemm96x2<<<gemm_blocks, 192, 0, stream>>>(bufH, Wsl, bsl, Wdl, bdl, bufT, bufFd, Nn);
        gat_agg<<<gat_blocks, 256, 0, stream>>>(bufT, bufFd, atl, row_start, csr_src, perm, bufH, Nn);
    }

    readout_partial<<<RB, 384, 0, stream>>>(bufH, graph_id, partial, Nn);
    readout_reduce<<<(GG * 96 + 255) / 256, 256, 0, stream>>>(partial, hg);
    mlp_kernel<<<GG, 96, 0, stream>>>(hg, Wc1, bc1, Wc2, bc2, Wc3, bc3, out);
}

// Round 10
// 633.576 us; speedup vs baseline: 1.2595x; 1.2595x over previous
//
#include <hip/hip_runtime.h>
#include <hip/hip_bf16.h>

#define Nn 50000
#define Ee 800000
#define INF_ 128
#define HIDF 96
#define HH 8
#define DD 12
#define GG 64
#define OUTF 10

#define SCAN_CHUNK 512
#define SCAN_BLOCKS ((Nn + SCAN_CHUNK - 1) / SCAN_CHUNK)   // 98
#define NSB ((Nn + 255) / 256)                             // 196
#define RB 128   // readout partial blocks

// byte-packed LDS histogram CSR build
#define HCHK 256                // edge chunks (= blocks)
#define HCHKE (Ee / HCHK)       // 3125 edges per chunk
#define NW 12512                // packed words: 4 keys/word, 50048 >= Nn
#define DBIN 64                 // degree bins for counting sort

// ---------------- hist pass A: single-pass dual byte-packed LDS histograms ----------------
// 2 x 12512 words = 100 KB LDS; grid = 256 blocks = 1/CU either way.
__global__ __launch_bounds__(512) void hist_lds(const int* __restrict__ src,
                                                const int* __restrict__ dst,
                                                unsigned int* __restrict__ partS,
                                                unsigned int* __restrict__ partD,
                                                unsigned char* __restrict__ edge_slot) {
    __shared__ unsigned int hS[NW];
    __shared__ unsigned int hD[NW];
    int b = blockIdx.x, t = threadIdx.x;
    for (int i = t; i < NW; i += 512) { hS[i] = 0u; hD[i] = 0u; }
    __syncthreads();
    int base = b * HCHKE;
    for (int i = t; i < HCHKE; i += 512) {
        int d = dst[base + i];
        unsigned int old = atomicAdd(&hD[d >> 2], 1u << ((d & 3) * 8));
        edge_slot[base + i] = (unsigned char)((old >> ((d & 3) * 8)) & 0xFFu);
        int s = src[base + i];
        atomicAdd(&hS[s >> 2], 1u << ((s & 3) * 8));
    }
    __syncthreads();
    for (int i = t; i < NW; i += 512) {
        partD[(size_t)b * NW + i] = hD[i];
        partS[(size_t)b * NW + i] = hS[i];
    }
}

// ---------------- hist pass B: packed chunk-prefix on partD; cnt_in, degs, degree-bin hist ----------------
__global__ __launch_bounds__(256) void hist_scan(unsigned int* __restrict__ partD,
                                                 const unsigned int* __restrict__ partS,
                                                 int* __restrict__ cnt_in,
                                                 float* __restrict__ degI_is,
                                                 float* __restrict__ degO_is,
                                                 int* __restrict__ dcnt) {
    __shared__ int hbin[DBIN];
    int t = threadIdx.x;
    if (t < DBIN) hbin[t] = 0;
    __syncthreads();
    int w = blockIdx.x * 256 + t;
    if (w < NW) {
        unsigned int run = 0u, totS = 0u;
        for (int b = 0; b < HCHK; ++b) {
            size_t idx = (size_t)b * NW + w;
            unsigned int v = partD[idx];
            partD[idx] = run;               // exclusive prefix across chunks (packed bytes)
            run += v;
            totS += partS[idx];
        }
#pragma unroll
        for (int j = 0; j < 4; ++j) {
            int k = w * 4 + j;
            if (k < Nn) {
                int di = (int)((run >> (j * 8)) & 0xFFu);
                int dо = (int)((totS >> (j * 8)) & 0xFFu);
                cnt_in[k] = di;
                degI_is[k] = rsqrtf((float)max(di, 1));
                degO_is[k] = rsqrtf((float)max(dо, 1));
                atomicAdd(&hbin[DBIN - 1 - min(di, DBIN - 1)], 1);
            }
        }
    }
    __syncthreads();
    if (t < DBIN && hbin[t]) atomicAdd(&dcnt[t], hbin[t]);
}

// ---------------- hierarchical scan, stage 1 ----------------
__global__ __launch_bounds__(256) void scan1_kernel(const int* __restrict__ cnt,
                                                    int* __restrict__ row_start,
                                                    int* __restrict__ blk_sum, int N) {
    __shared__ int part[256];
    int t = threadIdx.x;
    int base = blockIdx.x * SCAN_CHUNK;
    int i0 = base + 2 * t, i1 = i0 + 1;
    int a = (i0 < N) ? cnt[i0] : 0;
    int b = (i1 < N) ? cnt[i1] : 0;
    int s = a + b;
    part[t] = s;
    __syncthreads();
    for (int off = 1; off < 256; off <<= 1) {
        int v = (t >= off) ? part[t - off] : 0;
        __syncthreads();
        part[t] += v;
        __syncthreads();
    }
    int excl = part[t] - s;
    if (i0 < N) row_start[i0] = excl;
    if (i1 < N) row_start[i1] = excl + a;
    if (t == 255) blk_sum[blockIdx.x] = part[255];
}

// ---------------- stage 2 (block 0) + degree-bin scan (block 1) ----------------
__global__ __launch_bounds__(128) void scan2_kernel(const int* __restrict__ blk_sum,
                                                    int* __restrict__ blk_off,
                                                    int* __restrict__ row_start,
                                                    const int* __restrict__ dcnt,
                                                    int* __restrict__ dcur, int N) {
    __shared__ int part[128];
    int t = threadIdx.x;
    if (blockIdx.x == 0) {
        int v0 = (t < SCAN_BLOCKS) ? blk_sum[t] : 0;
        part[t] = v0;
        __syncthreads();
        for (int off = 1; off < 128; off <<= 1) {
            int v = (t >= off) ? part[t - off] : 0;
            __syncthreads();
            part[t] += v;
            __syncthreads();
        }
        blk_off[t] = part[t] - v0;
        if (t == 127) row_start[N] = part[127];
    } else {
        int v0 = (t < DBIN) ? dcnt[t] : 0;
        part[t] = v0;
        __syncthreads();
        for (int off = 1; off < DBIN; off <<= 1) {
            int v = (t >= off) ? part[t - off] : 0;
            __syncthreads();
            part[t] += v;
            __syncthreads();
        }
        if (t < DBIN) dcur[t] = part[t] - v0;   // exclusive
    }
}

// ---------------- stage 3 (blocks 0..SCAN_BLOCKS-1) + perm scatter (rest) ----------------
__global__ __launch_bounds__(256) void scan3_kernel(int* __restrict__ row_start,
                                                    const int* __restrict__ blk_off,
                                                    const int* __restrict__ cnt_in,
                                                    int* __restrict__ dcur,
                                                    int* __restrict__ perm, int N) {
    int t = threadIdx.x;
    if (blockIdx.x < SCAN_BLOCKS) {
        int base = blockIdx.x * SCAN_CHUNK;
        int off = blk_off[blockIdx.x];
        int i0 = base + 2 * t, i1 = i0 + 1;
        if (i0 < N) row_start[i0] += off;
        if (i1 < N) row_start[i1] += off;
    } else {
        __shared__ int lh[DBIN];
        __shared__ int lbase[DBIN];
        if (t < DBIN) lh[t] = 0;
        __syncthreads();
        int n = (blockIdx.x - SCAN_BLOCKS) * 256 + t;
        int bin = 0, lslot = 0;
        if (n < N) {
            bin = DBIN - 1 - min(cnt_in[n], DBIN - 1);
            lslot = atomicAdd(&lh[bin], 1);
        }
        __syncthreads();
        if (t < DBIN) lbase[t] = lh[t] ? atomicAdd(&dcur[t], lh[t]) : 0;
        __syncthreads();
        if (n < N) perm[lbase[bin] + lslot] = n;
    }
}

// ---------------- CSR fill: atomic-free ----------------
__global__ __launch_bounds__(512) void fill_kernel(const int* __restrict__ src,
                                                   const int* __restrict__ dst,
                                                   const int* __restrict__ row_start,
                                                   const unsigned int* __restrict__ partD,
                                                   const unsigned char* __restrict__ edge_slot,
                                                   int* __restrict__ csr_src) {
    int b = blockIdx.x, t = threadIdx.x;
    int base = b * HCHKE;
    size_t po = (size_t)b * NW;
    for (int i = t; i < HCHKE; i += 512) {
        int e = base + i;
        int d = dst[e];
        int cb = (int)((partD[po + (d >> 2)] >> ((d & 3) * 8)) & 0xFFu);
        csr_src[row_start[d] + cb + (int)edge_slot[e]] = src[e];
    }
}

// ---------------- staged-LDS GEMM: out[N x 96] = diag(rowScale) * A[N x K] @ W[K x 96] (+bias) ----------------
__global__ __launch_bounds__(192) void gemm96(const float* __restrict__ A, int K,
                                              const float* __restrict__ W,
                                              const float* __restrict__ bias,
                                              const float* __restrict__ rowScale,
                                              float* __restrict__ out, int N) {
    __shared__ float A_lds[64 * 36];
    __shared__ float W_lds[32 * 96];
    const int t = threadIdx.x;
    const int row0 = blockIdx.x * 64;
    const int tcol = t % 24;
    const int trow = t / 24;
    float acc[8][4];
#pragma unroll
    for (int i = 0; i < 8; ++i)
#pragma unroll
        for (int j = 0; j < 4; ++j) acc[i][j] = 0.f;

    for (int k0 = 0; k0 < K; k0 += 32) {
        for (int i = t; i < 32 * 24; i += 192) {
            ((float4*)W_lds)[i] = ((const float4*)W)[(size_t)k0 * 24 + i];
        }
        for (int i = t; i < 64 * 8; i += 192) {
            int r = i / 8, kk = i % 8;
            int gr = row0 + r;
            float4 v = make_float4(0.f, 0.f, 0.f, 0.f);
            if (gr < N) {
                v = *((const float4*)(A + (size_t)gr * K + k0 + kk * 4));
                if (rowScale) {
                    float s = rowScale[gr];
                    v.x *= s; v.y *= s; v.z *= s; v.w *= s;
                }
            }
            *((float4*)(A_lds + r * 36 + kk * 4)) = v;
        }
        __syncthreads();
#pragma unroll
        for (int kk4 = 0; kk4 < 8; ++kk4) {
            float4 a[8];
#pragma unroll
            for (int i = 0; i < 8; ++i)
                a[i] = *((const float4*)(A_lds + (trow + 8 * i) * 36 + kk4 * 4));
#pragma unroll
            for (int kk = 0; kk < 4; ++kk) {
                float4 wv = *((const float4*)(W_lds + (kk4 * 4 + kk) * 96 + tcol * 4));
#pragma unroll
                for (int i = 0; i < 8; ++i) {
                    float av = (kk == 0) ? a[i].x : (kk == 1) ? a[i].y : (kk == 2) ? a[i].z : a[i].w;
                    acc[i][0] = fmaf(av, wv.x, acc[i][0]);
                    acc[i][1] = fmaf(av, wv.y, acc[i][1]);
                    acc[i][2] = fmaf(av, wv.z, acc[i][2]);
                    acc[i][3] = fmaf(av, wv.w, acc[i][3]);
                }
            }
        }
        __syncthreads();
    }
    float4 b4 = bias ? *((const float4*)(bias + tcol * 4)) : make_float4(0.f, 0.f, 0.f, 0.f);
#pragma unroll
    for (int i = 0; i < 8; ++i) {
        int gr = row0 + trow + 8 * i;
        if (gr < N) {
            float4 o = make_float4(acc[i][0] + b4.x, acc[i][1] + b4.y,
                                   acc[i][2] + b4.z, acc[i][3] + b4.w);
            *((float4*)(out + (size_t)gr * 96 + tcol * 4)) = o;
        }
    }
}

// ---------------- dual GEMM: A read once, two weight sets, two outputs (K=96) ----------------
__global__ __launch_bounds__(192) void gemm96x2(const float* __restrict__ A,
                                                const float* __restrict__ W1_, const float* __restrict__ b1_,
                                                const float* __restrict__ W2_, const float* __restrict__ b2_,
                                                float* __restrict__ out1, float* __restrict__ out2, int N) {
    __shared__ float A_lds[64 * 36];
    __shared__ float W_lds[2 * 32 * 96];
    const int t = threadIdx.x;
    const int row0 = blockIdx.x * 64;
    const int tcol = t % 24;
    const int trow = t / 24;
    float acc1[8][4], acc2[8][4];
#pragma unroll
    for (int i = 0; i < 8; ++i)
#pragma unroll
        for (int j = 0; j < 4; ++j) { acc1[i][j] = 0.f; acc2[i][j] = 0.f; }

    for (int k0 = 0; k0 < 96; k0 += 32) {
        for (int i = t; i < 32 * 24; i += 192) {
            ((float4*)W_lds)[i] = ((const float4*)W1_)[(size_t)k0 * 24 + i];
            ((float4*)(W_lds + 32 * 96))[i] = ((const float4*)W2_)[(size_t)k0 * 24 + i];
        }
        for (int i = t; i < 64 * 8; i += 192) {
            int r = i / 8, kk = i % 8;
            int gr = row0 + r;
            float4 v = make_float4(0.f, 0.f, 0.f, 0.f);
            if (gr < N) v = *((const float4*)(A + (size_t)gr * 96 + k0 + kk * 4));
            *((float4*)(A_lds + r * 36 + kk * 4)) = v;
        }
        __syncthreads();
#pragma unroll
        for (int kk4 = 0; kk4 < 8; ++kk4) {
            float4 a[8];
#pragma unroll
            for (int i = 0; i < 8; ++i)
                a[i] = *((const float4*)(A_lds + (trow + 8 * i) * 36 + kk4 * 4));
#pragma unroll
            for (int kk = 0; kk < 4; ++kk) {
                float4 wv1 = *((const float4*)(W_lds + (kk4 * 4 + kk) * 96 + tcol * 4));
                float4 wv2 = *((const float4*)(W_lds + 32 * 96 + (kk4 * 4 + kk) * 96 + tcol * 4));
#pragma unroll
                for (int i = 0; i < 8; ++i) {
                    float av = (kk == 0) ? a[i].x : (kk == 1) ? a[i].y : (kk == 2) ? a[i].z : a[i].w;
                    acc1[i][0] = fmaf(av, wv1.x, acc1[i][0]);
                    acc1[i][1] = fmaf(av, wv1.y, acc1[i][1]);
                    acc1[i][2] = fmaf(av, wv1.z, acc1[i][2]);
                    acc1[i][3] = fmaf(av, wv1.w, acc1[i][3]);
                    acc2[i][0] = fmaf(av, wv2.x, acc2[i][0]);
                    acc2[i][1] = fmaf(av, wv2.y, acc2[i][1]);
                    acc2[i][2] = fmaf(av, wv2.z, acc2[i][2]);
                    acc2[i][3] = fmaf(av, wv2.w, acc2[i][3]);
                }
            }
        }
        __syncthreads();
    }
    float4 bb1 = *((const float4*)(b1_ + tcol * 4));
    float4 bb2 = *((const float4*)(b2_ + tcol * 4));
#pragma unroll
    for (int i = 0; i < 8; ++i) {
        int gr = row0 + trow + 8 * i;
        if (gr < N) {
            float4 o1 = make_float4(acc1[i][0] + bb1.x, acc1[i][1] + bb1.y,
                                    acc1[i][2] + bb1.z, acc1[i][3] + bb1.w);
            float4 o2 = make_float4(acc2[i][0] + bb2.x, acc2[i][1] + bb2.y,
                                    acc2[i][2] + bb2.z, acc2[i][3] + bb2.w);
            *((float4*)(out1 + (size_t)gr * 96 + tcol * 4)) = o1;
            *((float4*)(out2 + (size_t)gr * 96 + tcol * 4)) = o2;
        }
    }
}

// ---------------- GraphConv aggregate (degree-sorted via perm) ----------------
__global__ __launch_bounds__(192) void gc_agg(const float* __restrict__ hW,
                                              const int* __restrict__ row_start,
                                              const int* __restrict__ csr_src,
                                              const float* __restrict__ degI_is,
                                              const float* __restrict__ bias,
                                              const int* __restrict__ perm,
                                              float* __restrict__ hout, int N) {
    int tid = blockIdx.x * 192 + threadIdx.x;
    int p = tid / 24;
    int c = (tid % 24) * 4;
    if (p >= N) return;
    int n = perm[p];
    int beg = row_start[n], end = row_start[n + 1];
    float4 s = make_float4(0.f, 0.f, 0.f, 0.f);
    int e = beg;
    for (; e + 4 <= end; e += 4) {
        int i0 = csr_src[e], i1 = csr_src[e + 1], i2 = csr_src[e + 2], i3 = csr_src[e + 3];
        float4 v0 = *(const float4*)(hW + (size_t)i0 * 96 + c);
        float4 v1 = *(const float4*)(hW + (size_t)i1 * 96 + c);
        float4 v2 = *(const float4*)(hW + (size_t)i2 * 96 + c);
        float4 v3 = *(const float4*)(hW + (size_t)i3 * 96 + c);
        s.x += (v0.x + v1.x) + (v2.x + v3.x);
        s.y += (v0.y + v1.y) + (v2.y + v3.y);
        s.z += (v0.z + v1.z) + (v2.z + v3.z);
        s.w += (v0.w + v1.w) + (v2.w + v3.w);
    }
    for (; e < end; ++e) {
        int i0 = csr_src[e];
        float4 v0 = *(const float4*)(hW + (size_t)i0 * 96 + c);
        s.x += v0.x; s.y += v0.y; s.z += v0.z; s.w += v0.w;
    }
    float dn = degI_is[n];
    float4 b = *(const float4*)(bias + c);
    float4 o;
    o.x = fmaxf(fmaf(s.x, dn, b.x), 0.f);
    o.y = fmaxf(fmaf(s.y, dn, b.y), 0.f);
    o.z = fmaxf(fmaf(s.z, dn, b.z), 0.f);
    o.w = fmaxf(fmaf(s.w, dn, b.w), 0.f);
    *(float4*)(hout + (size_t)n * 96 + c) = o;
}

// ---------------- GATv2: dual independent online-softmax chains, merged at end ----------------
__global__ __launch_bounds__(256) void gat_agg(const float* __restrict__ fs,
                                               const float* __restrict__ fd,
                                               const float* __restrict__ attn,
                                               const int* __restrict__ row_start,
                                               const int* __restrict__ csr_src,
                                               const int* __restrict__ perm,
                                               float* __restrict__ hout, int N) {
    int tid = blockIdx.x * 256 + threadIdx.x;
    int p = tid >> 3, hd = tid & 7;
    if (p >= N) return;
    int n = perm[p];
    float att[12], fdv[12];
    {
        const float4* ap = (const float4*)(attn + hd * 12);
        float4 a0 = ap[0], a1 = ap[1], a2 = ap[2];
        att[0]=a0.x; att[1]=a0.y; att[2]=a0.z; att[3]=a0.w;
        att[4]=a1.x; att[5]=a1.y; att[6]=a1.z; att[7]=a1.w;
        att[8]=a2.x; att[9]=a2.y; att[10]=a2.z; att[11]=a2.w;
        const float4* dp = (const float4*)(fd + (size_t)n * 96 + hd * 12);
        float4 d0 = dp[0], d1 = dp[1], d2 = dp[2];
        fdv[0]=d0.x; fdv[1]=d0.y; fdv[2]=d0.z; fdv[3]=d0.w;
        fdv[4]=d1.x; fdv[5]=d1.y; fdv[6]=d1.z; fdv[7]=d1.w;
        fdv[8]=d2.x; fdv[9]=d2.y; fdv[10]=d2.z; fdv[11]=d2.w;
    }
    int beg = row_start[n], end = row_start[n + 1];
    float m0 = -3.0e38f, den0 = 0.f, m1 = -3.0e38f, den1 = 0.f;
    float A0[12], A1[12];
#pragma unroll
    for (int d = 0; d < 12; ++d) { A0[d] = 0.f; A1[d] = 0.f; }

    auto proc = [&](const float4& s0, const float4& s1, const float4& s2,
                    float& m, float& den, float* acc) {
        float fsv[12];
        fsv[0]=s0.x; fsv[1]=s0.y; fsv[2]=s0.z; fsv[3]=s0.w;
        fsv[4]=s1.x; fsv[5]=s1.y; fsv[6]=s1.z; fsv[7]=s1.w;
        fsv[8]=s2.x; fsv[9]=s2.y; fsv[10]=s2.z; fsv[11]=s2.w;
        float logit = 0.f;
#pragma unroll
        for (int d = 0; d < 12; ++d) {
            float u = fsv[d] + fdv[d];
            u = u > 0.f ? u : 0.2f * u;
            logit = fmaf(u, att[d], logit);
        }
        float nm = fmaxf(m, logit);
        float cc = __expf(m - nm);
        float w  = __expf(logit - nm);
        den = fmaf(den, cc, w);
#pragma unroll
        for (int d = 0; d < 12; ++d) acc[d] = fmaf(acc[d], cc, w * fsv[d]);
        m = nm;
    };

    int e = beg;
    for (; e + 4 <= end; e += 4) {
        int i0 = csr_src[e], i1 = csr_src[e + 1], i2 = csr_src[e + 2], i3 = csr_src[e + 3];
        const float4* p0 = (const float4*)(fs + (size_t)i0 * 96 + hd * 12);
        const float4* p1 = (const float4*)(fs + (size_t)i1 * 96 + hd * 12);
        const float4* p2 = (const float4*)(fs + (size_t)i2 * 96 + hd * 12);
        const float4* p3 = (const float4*)(fs + (size_t)i3 * 96 + hd * 12);
        float4 a0 = p0[0], a1 = p0[1], a2 = p0[2];
        float4 b0 = p1[0], b1 = p1[1], b2 = p1[2];
        float4 c0 = p2[0], c1 = p2[1], c2 = p2[2];
        float4 d0 = p3[0], d1 = p3[1], d2 = p3[2];
        proc(a0, a1, a2, m0, den0, A0);
        proc(b0, b1, b2, m1, den1, A1);
        proc(c0, c1, c2, m0, den0, A0);
        proc(d0, d1, d2, m1, den1, A1);
    }
    for (; e < end; ++e) {
        int i0 = csr_src[e];
        const float4* p0 = (const float4*)(fs + (size_t)i0 * 96 + hd * 12);
        float4 a0 = p0[0], a1 = p0[1], a2 = p0[2];
        proc(a0, a1, a2, m0, den0, A0);
    }
    // merge the two chains
    float nm = fmaxf(m0, m1);
    float c0 = __expf(m0 - nm), c1 = __expf(m1 - nm);
    float den = den0 * c0 + den1 * c1;
    float inv = den > 0.f ? 1.f / den : 0.f;
    float* op = hout + (size_t)n * 96 + hd * 12;
#pragma unroll
    for (int d = 0; d < 12; ++d)
        op[d] = fmaxf((A0[d] * c0 + A1[d] * c1) * inv, 0.f);
}

// ---------------- per-graph max readout: stage 1, per-block LDS max -> partials ----------------
__global__ __launch_bounds__(384) void readout_partial(const float* __restrict__ h,
                                                       const int* __restrict__ graph_id,
                                                       float* __restrict__ partial, int N) {
    __shared__ int lhg[GG * 96];
    int t = threadIdx.x;
    for (int i = t; i < GG * 96; i += 384) lhg[i] = 0;
    __syncthreads();
    int f = t % 96, nl = t / 96;
    for (int n0 = blockIdx.x * 4; n0 < N; n0 += RB * 4) {
        int n = n0 + nl;
        if (n < N) {
            int g = graph_id[n];
            float v = h[(size_t)n * 96 + f];
            atomicMax(&lhg[g * 96 + f], __float_as_int(v));
        }
    }
    __syncthreads();
    for (int i = t; i < GG * 96; i += 384)
        partial[(size_t)blockIdx.x * (GG * 96) + i] = __int_as_float(lhg[i]);
}

// ---------------- readout stage 2: reduce partials ----------------
__global__ void readout_reduce(const float* __restrict__ partial, float* __restrict__ hg) {
    int i = blockIdx.x * 256 + threadIdx.x;
    if (i < GG * 96) {
        float m = 0.f;
        for (int b = 0; b < RB; ++b) m = fmaxf(m, partial[(size_t)b * (GG * 96) + i]);
        hg[i] = m;
    }
}

// ---------------- classifier MLP: one block per graph ----------------
__global__ __launch_bounds__(96) void mlp_kernel(const float* __restrict__ hg,
                                                 const float* __restrict__ Wc1, const float* __restrict__ bc1,
                                                 const float* __restrict__ Wc2, const float* __restrict__ bc2,
                                                 const float* __restrict__ Wc3, const float* __restrict__ bc3,
                                                 float* __restrict__ out) {
    int g = blockIdx.x;
    int t = threadIdx.x;
    __shared__ float z0[96], z1[96], z2[48];
    z0[t] = hg[(size_t)g * 96 + t];
    __syncthreads();
    float s = bc1[t];
    for (int k = 0; k < 96; ++k) s = fmaf(z0[k], Wc1[k * 96 + t], s);
    z1[t] = fmaxf(s, 0.f);
    __syncthreads();
    if (t < 48) {
        float s2 = bc2[t];
        for (int k = 0; k < 96; ++k) s2 = fmaf(z1[k], Wc2[k * 48 + t], s2);
        z2[t] = fmaxf(s2, 0.f);
    }
    __syncthreads();
    if (t < 10) {
        float s3 = bc3[t];
        for (int k = 0; k < 48; ++k) s3 = fmaf(z2[k], Wc3[k * 10 + t], s3);
        out[(size_t)g * 10 + t] = s3;
    }
}

extern "C" void kernel_launch(void* const* d_in, const int* in_sizes, int n_in,
                              void* d_out, int out_size, void* d_ws, size_t ws_size,
                              hipStream_t stream) {
    const float* x        = (const float*)d_in[0];
    const int*   src      = (const int*)d_in[1];
    const int*   dst      = (const int*)d_in[2];
    const int*   graph_id = (const int*)d_in[3];
    const float* W1  = (const float*)d_in[4];
    const float* b1  = (const float*)d_in[5];
    const float* W2  = (const float*)d_in[6];
    const float* b2  = (const float*)d_in[7];
    const float* Ws  = (const float*)d_in[8];
    const float* bs  = (const float*)d_in[9];
    const float* Wd  = (const float*)d_in[10];
    const float* bd  = (const float*)d_in[11];
    const float* attn = (const float*)d_in[12];
    const float* Wc1 = (const float*)d_in[13];
    const float* bc1 = (const float*)d_in[14];
    const float* Wc2 = (const float*)d_in[15];
    const float* bc2 = (const float*)d_in[16];
    const float* Wc3 = (const float*)d_in[17];
    const float* bc3 = (const float*)d_in[18];
    float* out = (float*)d_out;

    char* ws = (char*)d_ws;
    size_t off = 0;
    auto alloc = [&](size_t bytes) {
        char* p = ws + off;
        off = (off + bytes + 255) & ~(size_t)255;
        return p;
    };
    int*   cnt_in    = (int*)alloc(Nn * 4);
    int*   row_start = (int*)alloc((Nn + 1) * 4);
    unsigned char* edge_slot = (unsigned char*)alloc(Ee);
    int*   csr_src   = (int*)alloc(Ee * 4);
    int*   perm      = (int*)alloc(Nn * 4);
    float* degI_is   = (float*)alloc(Nn * 4);
    float* degO_is   = (float*)alloc(Nn * 4);
    float* bufH      = (float*)alloc((size_t)Nn * 96 * 4);
    float* bufT      = (float*)alloc((size_t)Nn * 96 * 4);
    float* bufFd     = (float*)alloc((size_t)Nn * 96 * 4);
    float* hg        = (float*)alloc(GG * 96 * 4);
    float* partial   = (float*)alloc((size_t)RB * GG * 96 * 4);
    int*   blk_sum   = (int*)alloc(128 * 4);
    int*   blk_off   = (int*)alloc(128 * 4);
    int*   dcnt      = (int*)alloc(DBIN * 4);
    int*   dcur      = (int*)alloc(DBIN * 4);

    // packed histogram partials alias the (not-yet-used) feature buffers:
    // HCHK*NW*4 = 12.8 MB each; bufT/bufFd are 19.2 MB each.
    unsigned int* partS = (unsigned int*)bufT;
    unsigned int* partD = (unsigned int*)bufFd;

    hipMemsetAsync(dcnt, 0, DBIN * 4, stream);

    // ---- CSR build + degrees + degree-sort (no global fp atomics, 6 kernels) ----
    hist_lds<<<HCHK, 512, 0, stream>>>(src, dst, partS, partD, edge_slot);
    hist_scan<<<(NW + 255) / 256, 256, 0, stream>>>(partD, partS, cnt_in, degI_is, degO_is, dcnt);
    scan1_kernel<<<SCAN_BLOCKS, 256, 0, stream>>>(cnt_in, row_start, blk_sum, Nn);
    scan2_kernel<<<2, 128, 0, stream>>>(blk_sum, blk_off, row_start, dcnt, dcur, Nn);
    scan3_kernel<<<SCAN_BLOCKS + NSB, 256, 0, stream>>>(row_start, blk_off, cnt_in, dcur, perm, Nn);
    fill_kernel<<<HCHK, 512, 0, stream>>>(src, dst, row_start, partD, edge_slot, csr_src);

    int gemm_blocks = (Nn + 63) / 64;
    int agg_blocks  = (Nn * 24 + 191) / 192;
    int gat_blocks  = (Nn * 8 + 255) / 256;

    // GraphConv 1: x[N,128] -> bufH
    gemm96<<<gemm_blocks, 192, 0, stream>>>(x, 128, W1, nullptr, degO_is, bufT, Nn);
    gc_agg<<<agg_blocks, 192, 0, stream>>>(bufT, row_start, csr_src, degI_is, b1, perm, bufH, Nn);
    // GraphConv 2
    gemm96<<<gemm_blocks, 192, 0, stream>>>(bufH, 96, W2, nullptr, degO_is, bufT, Nn);
    gc_agg<<<agg_blocks, 192, 0, stream>>>(bufT, row_start, csr_src, degI_is, b2, perm, bufH, Nn);

    // 3x GATv2: fused dual GEMM (fs,fd) then fused attention+aggregate
    for (int l = 0; l < 3; ++l) {
        const float* Wsl = Ws + (size_t)l * 96 * 96;
        const float* bsl = bs + (size_t)l * 96;
        const float* Wdl = Wd + (size_t)l * 96 * 96;
        const float* bdl = bd + (size_t)l * 96;
        const float* atl = attn + (size_t)l * 96;
        gemm96x2<<<gemm_blocks, 192, 0, stream>>>(bufH, Wsl, bsl, Wdl, bdl, bufT, bufFd, Nn);
        gat_agg<<<gat_blocks, 256, 0, stream>>>(bufT, bufFd, atl, row_start, csr_src, perm, bufH, Nn);
    }

    readout_partial<<<RB, 384, 0, stream>>>(bufH, graph_id, partial, Nn);
    readout_reduce<<<(GG * 96 + 255) / 256, 256, 0, stream>>>(partial, hg);
    mlp_kernel<<<GG, 96, 0, stream>>>(hg, Wc1, bc1, Wc2, bc2, Wc3, bc3, out);
}